// Round 1
// baseline (5269.941 us; speedup 1.0000x reference)
//
#include <hip/hip_runtime.h>
#include <math.h>

#define SEQ   2048
#define BATCH 128
#define HID   256
#define OUTD  2

// One workgroup (256 threads = 4 waves) per batch element. Thread j owns
// hidden unit j: keeps W_eff[j,:] (256 fp32) in VGPRs, recurrent state h_j in
// a register. Per step: v=2h-1 broadcast through double-buffered LDS (one
// barrier/step), 256 FMAs/thread, sigmoid, store h to out.
// __launch_bounds__(256,1): 1 wave/SIMD -> up to 512 VGPRs, no spill for wrow.
__global__ __launch_bounds__(HID, 1)
void rnn_scan_kernel(const float* __restrict__ x,        // (SEQ, BATCH)
                     const float* __restrict__ h0,       // (BATCH, HID)
                     const float* __restrict__ W_ih,     // (HID, 1)
                     const float* __restrict__ W_hh,     // (HID, HID)
                     const float* __restrict__ W_hh_b,   // (HID, HID)
                     const float* __restrict__ b_h,      // (HID,)
                     const int*   __restrict__ context,  // scalar
                     float*       __restrict__ out_hs)   // (BATCH, SEQ, HID)
{
    const int b = blockIdx.x;
    const int j = threadIdx.x;

    __shared__ __align__(16) float v_lds[2][HID];
    __shared__ float x_lds[SEQ];

    // Stage this batch's x column into LDS (one-time, removes per-step global
    // load latency from the critical path).
    for (int t = j; t < SEQ; t += HID)
        x_lds[t] = x[t * BATCH + b];

    const float ctx = (float)context[0];

    // W_eff row j -> registers (fully unrolled, constant indices => VGPRs).
    float wrow[HID];
    {
        const float* wr = W_hh   + (size_t)j * HID;
        const float* br = W_hh_b + (size_t)j * HID;
        #pragma unroll
        for (int k = 0; k < HID; k += 4) {
            const float4 a = *(const float4*)(wr + k);
            const float4 c = *(const float4*)(br + k);
            wrow[k + 0] = a.x + ctx * c.x;
            wrow[k + 1] = a.y + ctx * c.y;
            wrow[k + 2] = a.z + ctx * c.z;
            wrow[k + 3] = a.w + ctx * c.w;
        }
    }

    float h = h0[(size_t)b * HID + j];
    const float winj = W_ih[j];
    const float bhj  = b_h[j];

    float* outp = out_hs + (size_t)b * SEQ * HID + j;

    __syncthreads();  // x_lds ready

    for (int t = 0; t < SEQ; ++t) {
        const float* vbuf = v_lds[t & 1];
        v_lds[t & 1][j] = 2.0f * h - 1.0f;
        __syncthreads();
        // Double-buffered: next iteration writes the other buffer, so one
        // barrier per step is sufficient.

        const float xt = x_lds[t];

        // 8 independent accumulator chains: FMA latency ~4cyc, issue 2cyc ->
        // need >=2 chains; 8 keeps the VALU saturated.
        float a0 = 0.f, a1 = 0.f, a2 = 0.f, a3 = 0.f;
        float a4 = 0.f, a5 = 0.f, a6 = 0.f, a7 = 0.f;
        #pragma unroll
        for (int k = 0; k < HID; k += 8) {
            const float4 v0 = *(const float4*)(vbuf + k);
            const float4 v1 = *(const float4*)(vbuf + k + 4);
            a0 += wrow[k + 0] * v0.x;
            a1 += wrow[k + 1] * v0.y;
            a2 += wrow[k + 2] * v0.z;
            a3 += wrow[k + 3] * v0.w;
            a4 += wrow[k + 4] * v1.x;
            a5 += wrow[k + 5] * v1.y;
            a6 += wrow[k + 6] * v1.z;
            a7 += wrow[k + 7] * v1.w;
        }
        const float pre = (((a0 + a1) + (a2 + a3)) + ((a4 + a5) + (a6 + a7)))
                          + bhj + xt * winj;

        h = 1.0f / (1.0f + __expf(-pre));
        outp[(size_t)t * HID] = h;
    }
}

// y[b,t] = sum_j out[b,t,j] * W[0,j] + bias[0]. One wave per row: lane l holds
// W0[4l..4l+3], loads the matching float4 of the row (coalesced 1KB/wave),
// butterfly shfl reduction over 64 lanes.
__global__ __launch_bounds__(256, 4)
void head_kernel(const float* __restrict__ hs,   // (BATCH, SEQ, HID)
                 const float* __restrict__ W,    // (OUTD, HID)
                 const float* __restrict__ bias, // (OUTD,)
                 float*       __restrict__ y)    // (BATCH*SEQ,)
{
    const int lane   = threadIdx.x & 63;
    const int gwave  = (blockIdx.x * blockDim.x + threadIdx.x) >> 6;
    const int nwaves = (gridDim.x * blockDim.x) >> 6;

    const float4 w0 = *(const float4*)(W + lane * 4);
    const float  b0 = bias[0];

    const int nrows = BATCH * SEQ;
    for (int r = gwave; r < nrows; r += nwaves) {
        const float4 hv = *(const float4*)(hs + (size_t)r * HID + lane * 4);
        float s = hv.x * w0.x + hv.y * w0.y + hv.z * w0.z + hv.w * w0.w;
        #pragma unroll
        for (int off = 32; off; off >>= 1)
            s += __shfl_xor(s, off, 64);
        if (lane == 0) y[r] = s + b0;
    }
}

extern "C" void kernel_launch(void* const* d_in, const int* in_sizes, int n_in,
                              void* d_out, int out_size, void* d_ws, size_t ws_size,
                              hipStream_t stream) {
    const float* x      = (const float*)d_in[0];
    const float* h0     = (const float*)d_in[1];
    const float* W_ih   = (const float*)d_in[2];
    const float* W_hh   = (const float*)d_in[3];
    const float* W_hh_b = (const float*)d_in[4];
    const float* b_h    = (const float*)d_in[5];
    const float* W      = (const float*)d_in[6];
    const float* bias   = (const float*)d_in[7];
    const int*   ctx    = (const int*)d_in[8];

    float* y  = (float*)d_out;                // (BATCH*SEQ,) = y[:,:,0]
    float* hs = y + (size_t)BATCH * SEQ;      // (BATCH, SEQ, HID) = out

    rnn_scan_kernel<<<BATCH, HID, 0, stream>>>(x, h0, W_ih, W_hh, W_hh_b,
                                               b_h, ctx, hs);
    head_kernel<<<2048, 256, 0, stream>>>(hs, W, bias, y);
}

// Round 2
// 1512.951 us; speedup vs baseline: 3.4832x; 3.4832x over previous
//
#include <hip/hip_runtime.h>
#include <math.h>

#define SEQ   2048
#define BATCH 128
#define HID   256
#define OUTD  2
#define NW    8            // waves per block
#define KS    (HID / NW)   // 32: k-slice per wave

// One block (512 threads = 8 waves) per batch element.
// K-split: wave w owns k-slice [32w,32w+32); lane l computes rows 4l..4l+3
// over that slice, holding W_eff[4l+i][32w..+32) in 32 float4 REGISTERS
// (128 VGPRs; __launch_bounds__(512,2) -> 256 VGPR budget, 2 waves/SIMD).
// Per step: 8 broadcast ds_read_b128 of v per thread, 128 FMAs, float4
// partial write to LDS, barrier, threads<256 reduce 8 partials + sigmoid,
// write v back to LDS, barrier. 64 broadcast LDS reads/CU/step (4x fewer
// than the row-per-thread design, which needed waves*64).
__global__ __launch_bounds__(512, 2)
void rnn_scan_kernel(const float* __restrict__ x,        // (SEQ, BATCH)
                     const float* __restrict__ h0,       // (BATCH, HID)
                     const float* __restrict__ W_ih,     // (HID, 1)
                     const float* __restrict__ W_hh,     // (HID, HID)
                     const float* __restrict__ W_hh_b,   // (HID, HID)
                     const float* __restrict__ b_h,      // (HID,)
                     const int*   __restrict__ context,  // scalar
                     float*       __restrict__ out_hs)   // (BATCH, SEQ, HID)
{
    const int b   = blockIdx.x;
    const int tid = threadIdx.x;
    const int w   = tid >> 6;   // wave 0..7
    const int l   = tid & 63;   // lane

    __shared__ __align__(16) float v_lds[HID];        // 2h-1, single buffer
    __shared__ __align__(16) float part[NW][HID];     // per-wave partials
    __shared__ float x_lds[SEQ];

    // Stage x column (one-time; L2-resident source).
    for (int t = tid; t < SEQ; t += 512)
        x_lds[t] = x[t * BATCH + b];

    const float ctx = (float)context[0];

    // Weights: wr_[i][c] = W_eff[4l+i][KS*w + 4c .. +3]. Small unrolled
    // loops with constant indices -> SROA promotes to 128 VGPRs.
    float4 wr_[4][8];
    #pragma unroll
    for (int i = 0; i < 4; ++i) {
        const float* wp = W_hh   + (size_t)(4 * l + i) * HID + KS * w;
        const float* bp = W_hh_b + (size_t)(4 * l + i) * HID + KS * w;
        #pragma unroll
        for (int c = 0; c < 8; ++c) {
            const float4 a = *(const float4*)(wp + 4 * c);
            const float4 d = *(const float4*)(bp + 4 * c);
            wr_[i][c] = make_float4(a.x + ctx * d.x, a.y + ctx * d.y,
                                    a.z + ctx * d.z, a.w + ctx * d.w);
        }
    }

    // Recurrent state: thread j<256 owns h_j (j == row).
    float h = 0.f, winj = 0.f, bhj = 0.f;
    if (tid < HID) {
        h    = h0[(size_t)b * HID + tid];
        winj = W_ih[tid];
        bhj  = b_h[tid];
        v_lds[tid] = 2.f * h - 1.f;
    }
    float* outp = out_hs + (size_t)b * SEQ * HID + tid;

    __syncthreads();  // v_lds + x_lds ready

    const float4* vbuf = (const float4*)v_lds + w * (KS / 4);

    for (int t = 0; t < SEQ; ++t) {
        // Phase 1: partial dot over my k-slice for 4 rows.
        float p0 = 0.f, p1 = 0.f, p2 = 0.f, p3 = 0.f;
        #pragma unroll
        for (int c = 0; c < 8; ++c) {
            const float4 v4 = vbuf[c];       // broadcast read (same addr/wave)
            const float4 w0 = wr_[0][c];
            const float4 w1 = wr_[1][c];
            const float4 w2 = wr_[2][c];
            const float4 w3 = wr_[3][c];
            p0 += w0.x * v4.x; p0 += w0.y * v4.y; p0 += w0.z * v4.z; p0 += w0.w * v4.w;
            p1 += w1.x * v4.x; p1 += w1.y * v4.y; p1 += w1.z * v4.z; p1 += w1.w * v4.w;
            p2 += w2.x * v4.x; p2 += w2.y * v4.y; p2 += w2.z * v4.z; p2 += w2.w * v4.w;
            p3 += w3.x * v4.x; p3 += w3.y * v4.y; p3 += w3.z * v4.z; p3 += w3.w * v4.w;
        }
        *(float4*)(&part[w][4 * l]) = make_float4(p0, p1, p2, p3);

        __syncthreads();  // partials ready; all v reads done

        // Phase 2: reduce + sigmoid by the 256 row-owner threads.
        if (tid < HID) {
            const float s = ((part[0][tid] + part[1][tid]) +
                             (part[2][tid] + part[3][tid])) +
                            ((part[4][tid] + part[5][tid]) +
                             (part[6][tid] + part[7][tid]));
            const float pre = s + bhj + x_lds[t] * winj;
            h = 1.f / (1.f + __expf(-pre));
            v_lds[tid] = 2.f * h - 1.f;       // safe: all reads were pre-barrier
            outp[(size_t)t * HID] = h;        // coalesced 1KB store
        }
        __syncthreads();  // v ready for next step
    }
}

// y[b,t] = dot(hs[b,t,:], W[0,:]) + bias[0]. One wave per row, butterfly
// shfl reduction; rows are L2/L3-resident right after the scan.
__global__ __launch_bounds__(256, 4)
void head_kernel(const float* __restrict__ hs,   // (BATCH, SEQ, HID)
                 const float* __restrict__ W,    // (OUTD, HID)
                 const float* __restrict__ bias, // (OUTD,)
                 float*       __restrict__ y)    // (BATCH*SEQ,)
{
    const int lane   = threadIdx.x & 63;
    const int gwave  = (blockIdx.x * blockDim.x + threadIdx.x) >> 6;
    const int nwaves = (gridDim.x * blockDim.x) >> 6;

    const float4 w0 = *(const float4*)(W + lane * 4);
    const float  b0 = bias[0];

    const int nrows = BATCH * SEQ;
    for (int r = gwave; r < nrows; r += nwaves) {
        const float4 hv = *(const float4*)(hs + (size_t)r * HID + lane * 4);
        float s = hv.x * w0.x + hv.y * w0.y + hv.z * w0.z + hv.w * w0.w;
        #pragma unroll
        for (int off = 32; off; off >>= 1)
            s += __shfl_xor(s, off, 64);
        if (lane == 0) y[r] = s + b0;
    }
}

extern "C" void kernel_launch(void* const* d_in, const int* in_sizes, int n_in,
                              void* d_out, int out_size, void* d_ws, size_t ws_size,
                              hipStream_t stream) {
    const float* x      = (const float*)d_in[0];
    const float* h0     = (const float*)d_in[1];
    const float* W_ih   = (const float*)d_in[2];
    const float* W_hh   = (const float*)d_in[3];
    const float* W_hh_b = (const float*)d_in[4];
    const float* b_h    = (const float*)d_in[5];
    const float* W      = (const float*)d_in[6];
    const float* bias   = (const float*)d_in[7];
    const int*   ctx    = (const int*)d_in[8];

    float* y  = (float*)d_out;                // (BATCH*SEQ,) = y[:,:,0]
    float* hs = y + (size_t)BATCH * SEQ;      // (BATCH, SEQ, HID) = out

    rnn_scan_kernel<<<BATCH, 512, 0, stream>>>(x, h0, W_ih, W_hh, W_hh_b,
                                               b_h, ctx, hs);
    head_kernel<<<2048, 256, 0, stream>>>(hs, W, bias, y);
}